// Round 1
// baseline (230.846 us; speedup 1.0000x reference)
//
#include <hip/hip_runtime.h>

#define N 9216
#define CIN 256
#define DQ 32
#define NT 144                      // N / 64
#define LOG2E 1.44269504088896340736f

typedef short short8 __attribute__((ext_vector_type(8)));   // 8 bf16 in 4 VGPRs
typedef float floatx4 __attribute__((ext_vector_type(4)));
typedef unsigned short ushort_t;

__device__ __forceinline__ ushort_t f2bf(float f) {
  union { float f; unsigned u; } a; a.f = f;
  unsigned u = a.u;
  u += 0x7fffu + ((u >> 16) & 1u);   // round-to-nearest-even
  return (ushort_t)(u >> 16);
}
// cheap round-to-nearest: 2 VALU ops instead of 5.
__device__ __forceinline__ ushort_t f2bf_fast(float f) {
  union { float f; unsigned u; } a; a.f = f;
  return (ushort_t)((a.u + 0x8000u) >> 16);
}
__device__ __forceinline__ float bf2f(ushort_t h) {
  union { unsigned u; float f; } a; a.u = ((unsigned)h) << 16;
  return a.f;
}
// pack two floats -> one uint of 2 bf16 (lo = c, hi = c1)
__device__ __forceinline__ unsigned pack2(float lo, float hi) {
  return ((unsigned)f2bf_fast(hi) << 16) | (unsigned)f2bf_fast(lo);
}
// 8 consecutive fp32 -> bf16x8 A-fragment
__device__ __forceinline__ short8 mk_bf16x8(const float* p) {
  float4 f0 = *(const float4*)(p);
  float4 f1 = *(const float4*)(p + 4);
  union { unsigned u[4]; short8 v; } r;
  r.u[0] = pack2(f0.x, f0.y);
  r.u[1] = pack2(f0.z, f0.w);
  r.u[2] = pack2(f1.x, f1.y);
  r.u[3] = pack2(f1.z, f1.w);
  return r.v;
}

// ---------------------------------------------------------------------------
// Shared staging: x tile (256 c x 64 n) -> LDS bf16 xbT[n][k=c] (B-frag
// layout: row n, k contiguous; +8 ushort pad -> 528 B row stride, 16B-aligned
// reads).  Thread t: c-pair p = t&31 (per 64-c chunk), n-group ng = t>>5;
// packs (c, c+1) into b32 writes -- consecutive uints across lanes, no bank
// conflicts.
// ---------------------------------------------------------------------------
#define XBT_STRIDE 264   // ushorts per row (256 + 8 pad); 132 uints

__device__ __forceinline__ void stage_x_tile(
    const float* __restrict__ x, int n0, int t, ushort_t (*xbT)[XBT_STRIDE])
{
  const int p = t & 31, ng = t >> 5;          // ng in [0,8)
  unsigned* base = (unsigned*)&xbT[0][0] + (size_t)(ng * 8) * 132;
#pragma unroll
  for (int cc = 0; cc < 4; ++cc) {
    const int c = cc * 64 + 2 * p;
    const float* r0 = x + (size_t)c * N + n0 + ng * 8;
    const float* r1 = r0 + N;
    float4 a0 = *(const float4*)(r0);
    float4 a1 = *(const float4*)(r0 + 4);
    float4 b0 = *(const float4*)(r1);
    float4 b1 = *(const float4*)(r1 + 4);
    unsigned* d = base + (cc * 32 + p);
    d[0 * 132] = pack2(a0.x, b0.x);
    d[1 * 132] = pack2(a0.y, b0.y);
    d[2 * 132] = pack2(a0.z, b0.z);
    d[3 * 132] = pack2(a0.w, b0.w);
    d[4 * 132] = pack2(a1.x, b1.x);
    d[5 * 132] = pack2(a1.y, b1.y);
    d[6 * 132] = pack2(a1.z, b1.z);
    d[7 * 132] = pack2(a1.w, b1.w);
  }
}

// ---------------------------------------------------------------------------
// Kernel 1: q/k/v projections via bf16 MFMA.  UNCHANGED (control).
// ---------------------------------------------------------------------------
__global__ __launch_bounds__(256) void qkv_mfma(
    const float* __restrict__ x,
    const float* __restrict__ Wq, const float* __restrict__ bq,
    const float* __restrict__ Wk, const float* __restrict__ bk,
    const float* __restrict__ Wv, const float* __restrict__ bv,
    ushort_t* __restrict__ qT, ushort_t* __restrict__ kT,
    ushort_t* __restrict__ vG, float* __restrict__ sumExp)
{
  if (blockIdx.x == 0 && blockIdx.y == 0 && threadIdx.x == 0) *sumExp = 0.f;

  __shared__ ushort_t xbT[64][XBT_STRIDE];
  const int t = threadIdx.x;
  const int n0 = blockIdx.x * 64;
  const int oc = blockIdx.y;                 // 0: q(32)+k(32); 1..4: v
  const int w = t >> 6, lane = t & 63;
  const int quad = lane >> 4, l15 = lane & 15;

  stage_x_tile(x, n0, t, xbT);
  __syncthreads();

  const int obase = oc * 64 + w * 16;
  const int oA = obase + l15;                // A-frag row (m = l15)
  const float* Arow;
  if (oc == 0) Arow = (obase < 32) ? (Wq + (size_t)oA * CIN)
                                   : (Wk + (size_t)(oA - 32) * CIN);
  else         Arow = Wv + (size_t)(oA - 64) * CIN;

  floatx4 acc[4];
#pragma unroll
  for (int b2 = 0; b2 < 4; ++b2) acc[b2] = (floatx4){0.f, 0.f, 0.f, 0.f};

#pragma unroll
  for (int ks = 0; ks < 8; ++ks) {
    const short8 af = mk_bf16x8(Arow + ks * 32 + 8 * quad);
#pragma unroll
    for (int b2 = 0; b2 < 4; ++b2) {
      const short8 bf = *(const short8*)&xbT[b2 * 16 + l15][ks * 32 + 8 * quad];
      acc[b2] = __builtin_amdgcn_mfma_f32_16x16x32_bf16(af, bf, acc[b2], 0, 0, 0);
    }
  }

  // Epilogue.  C-layout: col = l15 (n within subtile), row = 4*quad + r (o).
#pragma unroll
  for (int b2 = 0; b2 < 4; ++b2) {
    const int n = n0 + b2 * 16 + l15;
#pragma unroll
    for (int r = 0; r < 4; ++r) {
      const int o = obase + 4 * quad + r;
      const float val = acc[b2][r];
      if (oc == 0) {
        if (o < 32) qT[(size_t)n * DQ + o]        = f2bf((val + bq[o]) * LOG2E);
        else        kT[(size_t)n * DQ + (o - 32)] = f2bf(val + bk[o - 32]);
      } else        vG[(size_t)(o - 64) * N + n]  = f2bf(val + bv[o - 64]);
    }
  }
}

// ---------------------------------------------------------------------------
// Kernel 2: flash attention, 32-m tiles.  R9: 512 threads = 8 waves.
// Previous version: 4 waves, acc[4][4] = 64 AGPR + 64 VGPR = 128 regs/wave
// -> 16-wave/CU reg cap, grid delivered ~12 waves/CU (Occupancy 37%,
// MfmaUtil 17%) -> latency-bound.  Now each wave owns a 32-channel strip
// (acc[2][4] = 32 AGPR) and exactly one QK subtile: wave w = (nq = w&3,
// mq = w>>2) computes P[16 nq rows][16 mq cols]; PV uses cw = 32*w.
// Same grid, same LDS layout, same total MFMA count; regs/wave ~72-80 ->
// 3 blocks x 8 waves = 24 waves/CU.  setprio(1) around PV cluster (T5).
// ---------------------------------------------------------------------------
__global__ __launch_bounds__(512, 6) void attn_kernel(
    const ushort_t* __restrict__ qT, const ushort_t* __restrict__ kT,
    const ushort_t* __restrict__ vG,
    ushort_t* __restrict__ Opart, float* __restrict__ lpart,
    int base, int rem)
{
  __shared__ ushort_t Pb[2][64][36];    // double-buffered P tile (64n x 32m)
  __shared__ float lred[2][64];         // per-m-half row-sum partials

  const int t = threadIdx.x;
  const int w = t >> 6;                 // 0..7
  const int lane = t & 63;
  const int quad = lane >> 4;
  const int l15 = lane & 15;
  const int nq = w & 3;                 // QK n-subtile owned by this wave
  const int mq = w >> 2;                // QK m-half owned by this wave
  const int nt = blockIdx.x;
  const int s  = blockIdx.y;
  const int n0 = nt * 64;
  const int sliceIters = base + (s < rem ? 1 : 0);
  const int it0 = s * base + (s < rem ? s : rem);
  const int mbase = it0 * 32;
  const int cw = w * 32;                // 32-channel strip for PV

  const short8 aq =
      *(const short8*)(qT + (size_t)(n0 + 16 * nq + l15) * DQ + 8 * quad);

  floatx4 acc[2][4];
#pragma unroll
  for (int a2 = 0; a2 < 2; ++a2)
#pragma unroll
    for (int b2 = 0; b2 < 4; ++b2)
      acc[a2][b2] = (floatx4){0.f, 0.f, 0.f, 0.f};
  float lsum[4] = {0.f, 0.f, 0.f, 0.f};
  const floatx4 z4 = {0.f, 0.f, 0.f, 0.f};

  // incrementing pointers: keep per-iter address math off the VALU
  const ushort_t* kPtr =
      kT + (size_t)(mbase + 16 * mq + l15) * DQ + 8 * quad;
  const ushort_t* vPtr =
      vG + (size_t)(cw + l15) * N + mbase + 8 * quad;

  for (int it = 0; it < sliceIters; ++it) {
    const short8 kb = *(const short8*)(kPtr);
    kPtr += 32 * DQ;
    floatx4 sv = __builtin_amdgcn_mfma_f32_16x16x32_bf16(aq, kb, z4, 0, 0, 0);

    // issue V loads early; ~L2 latency hides under exp/pack/barrier
    const short8 av0 = *(const short8*)(vPtr);
    const short8 av1 = *(const short8*)(vPtr + (size_t)16 * N);
    vPtr += 32;

    ushort_t* pb = &Pb[it & 1][0][0];
#pragma unroll
    for (int r = 0; r < 4; ++r) {
      float p = exp2f(sv[r]);
      lsum[r] += p;
      pb[(16 * nq + 4 * quad + r) * 36 + 16 * mq + l15] = f2bf_fast(p);
    }
    __syncthreads();

    __builtin_amdgcn_s_setprio(1);
#pragma unroll
    for (int b2 = 0; b2 < 4; ++b2) {
      const ushort_t* pr = pb + (b2 * 16 + l15) * 36 + 8 * quad;
      union { uint2 u2[2]; short8 v; } u;
      u.u2[0] = *(const uint2*)(pr);
      u.u2[1] = *(const uint2*)(pr + 4);
      const short8 pf = u.v;
      acc[0][b2] = __builtin_amdgcn_mfma_f32_16x16x32_bf16(av0, pf, acc[0][b2], 0, 0, 0);
      acc[1][b2] = __builtin_amdgcn_mfma_f32_16x16x32_bf16(av1, pf, acc[1][b2], 0, 0, 0);
    }
    __builtin_amdgcn_s_setprio(0);
  }

  // row-sum: reduce over l15 (m within this wave's half), combine the two
  // m-halves through LDS.
#pragma unroll
  for (int r = 0; r < 4; ++r) {
    float v = lsum[r];
    v += __shfl_xor(v, 1);
    v += __shfl_xor(v, 2);
    v += __shfl_xor(v, 4);
    v += __shfl_xor(v, 8);
    lsum[r] = v;
  }
  if (l15 == 0) {
#pragma unroll
    for (int r = 0; r < 4; ++r)
      lred[mq][16 * nq + 4 * quad + r] = lsum[r];
  }
  __syncthreads();
  if (t < 64)
    lpart[(size_t)s * N + n0 + t] = lred[0][t] + lred[1][t];

  const size_t basep = ((size_t)s * NT + nt) * 256;
#pragma unroll
  for (int a2 = 0; a2 < 2; ++a2)
#pragma unroll
    for (int b2 = 0; b2 < 4; ++b2)
#pragma unroll
      for (int r = 0; r < 4; ++r) {
        const int c  = cw + a2 * 16 + 4 * quad + r;
        const int nl = b2 * 16 + l15;
        Opart[(basep + c) * 64 + nl] = f2bf(acc[a2][b2][r]);
      }
}

// ---------------------------------------------------------------------------
// Kernel 3: fused combine + gate-exp.  UNCHANGED (control).
// ---------------------------------------------------------------------------
template<int NSL>
__global__ __launch_bounds__(1024) void cco_kernel(
    const ushort_t* __restrict__ Opart, const float* __restrict__ lpart,
    float* __restrict__ e_buf, float* __restrict__ sumExp)
{
  const int nt = blockIdx.x;
  const int t = threadIdx.x;
  const int n = t & 63, ci = t >> 6;   // ci in [0,16)
  float mx = -3.4e38f, sm = 0.f;
#pragma unroll
  for (int k = 0; k < 16; ++k) {
    const int c = ci * 16 + k;
    float val = 0.f;
#pragma unroll
    for (int s2 = 0; s2 < NSL; ++s2)
      val += bf2f(Opart[(((size_t)s2 * NT + nt) * 256 + c) * 64 + n]);
    mx = fmaxf(mx, val);
    sm += val;
  }
  __shared__ float rmx[16][64], rsm[16][64];
  rmx[ci][n] = mx; rsm[ci][n] = sm;
  __syncthreads();
  if (t < 64) {
    float m = rmx[0][t], s = rsm[0][t];
#pragma unroll
    for (int g = 1; g < 16; ++g) { m = fmaxf(m, rmx[g][t]); s += rsm[g][t]; }
    float l = 0.f;
#pragma unroll
    for (int s3 = 0; s3 < NSL; ++s3) l += lpart[(size_t)s3 * N + nt * 64 + t];
    const float oc = (m + s * (1.0f / 256.0f)) / l;
    const float ev = exp2f(oc * (0.0625f * LOG2E));
    e_buf[nt * 64 + t] = ev;
    float vs = ev;
    vs += __shfl_xor(vs, 1);  vs += __shfl_xor(vs, 2);
    vs += __shfl_xor(vs, 4);  vs += __shfl_xor(vs, 8);
    vs += __shfl_xor(vs, 16); vs += __shfl_xor(vs, 32);
    if (t == 0) atomicAdd(sumExp, vs);
  }
}

// ---------------------------------------------------------------------------
// Kernel 4: final 1x1 conv via bf16 MFMA + fp32 epilogue.  UNCHANGED (control).
// ---------------------------------------------------------------------------
__global__ __launch_bounds__(256) void final_mfma(
    const float* __restrict__ x, const float* __restrict__ W6,
    const float* __restrict__ b6, const float* __restrict__ gamma,
    const float* __restrict__ e_buf, const float* __restrict__ sumExp,
    float* __restrict__ out)
{
  __shared__ ushort_t xbT[64][XBT_STRIDE];
  const int t = threadIdx.x;
  const int n0 = blockIdx.x * 64;
  const int w = t >> 6, lane = t & 63;
  const int quad = lane >> 4, l15 = lane & 15;

  stage_x_tile(x, n0, t, xbT);
  __syncthreads();

  const int obase = blockIdx.y * 64 + w * 16;
  const float* Arow = W6 + (size_t)(obase + l15) * CIN;

  floatx4 acc[4];
#pragma unroll
  for (int b2 = 0; b2 < 4; ++b2) acc[b2] = (floatx4){0.f, 0.f, 0.f, 0.f};

#pragma unroll
  for (int ks = 0; ks < 8; ++ks) {
    const short8 af = mk_bf16x8(Arow + ks * 32 + 8 * quad);
#pragma unroll
    for (int b2 = 0; b2 < 4; ++b2) {
      const short8 bf = *(const short8*)&xbT[b2 * 16 + l15][ks * 32 + 8 * quad];
      acc[b2] = __builtin_amdgcn_mfma_f32_16x16x32_bf16(af, bf, acc[b2], 0, 0, 0);
    }
  }

  const float g1 = 1.0f + gamma[0];
  const float inv = 1.0f / sumExp[0];
#pragma unroll
  for (int b2 = 0; b2 < 4; ++b2) {
    const int n = n0 + b2 * 16 + l15;
    const float xc = e_buf[n] * inv;
#pragma unroll
    for (int r = 0; r < 4; ++r) {
      const int o = obase + 4 * quad + r;
      const float xv = x[(size_t)o * N + n];
      out[(size_t)o * N + n] = xv + g1 * (xc * acc[b2][r] + b6[o]);
    }
  }
}

// ---------------------------------------------------------------------------
extern "C" void kernel_launch(void* const* d_in, const int* in_sizes, int n_in,
                              void* d_out, int out_size, void* d_ws, size_t ws_size,
                              hipStream_t stream)
{
  const float* x     = (const float*)d_in[0];
  const float* Wq    = (const float*)d_in[1];
  const float* bq    = (const float*)d_in[2];
  const float* Wk    = (const float*)d_in[3];
  const float* bk    = (const float*)d_in[4];
  const float* Wv    = (const float*)d_in[5];
  const float* bv    = (const float*)d_in[6];
  const float* W6    = (const float*)d_in[7];
  const float* b6    = (const float*)d_in[8];
  const float* gamma = (const float*)d_in[9];
  float* out = (float*)d_out;

  const size_t fixed = (size_t)N * DQ * 2 * 2        // qT,kT
                     + (size_t)CIN * N * 2            // vG
                     + (size_t)N * 4                  // e_buf
                     + 256;                           // sumExp (+pad)
  int nsl = 7;
  size_t need = fixed + (size_t)nsl * NT * 256 * 64 * 2 + (size_t)nsl * N * 4;
  if (ws_size < need) nsl = 4;
  const int totIters = N / 32;                        // 288
  const int base = totIters / nsl;
  const int rem  = totIters % nsl;

  char* ws = (char*)d_ws;
  const size_t OFF_QT = 0;
  const size_t OFF_KT = OFF_QT + (size_t)N * DQ * 2;
  const size_t OFF_V  = OFF_KT + (size_t)N * DQ * 2;
  const size_t OFF_OP = OFF_V  + (size_t)CIN * N * 2;
  const size_t OFF_LP = OFF_OP + (size_t)nsl * NT * 256 * 64 * 2;
  const size_t OFF_EB = OFF_LP + (size_t)nsl * N * 4;
  const size_t OFF_SE = OFF_EB + (size_t)N * 4;

  ushort_t* qT     = (ushort_t*)(ws + OFF_QT);
  ushort_t* kT     = (ushort_t*)(ws + OFF_KT);
  ushort_t* vG     = (ushort_t*)(ws + OFF_V);
  ushort_t* Opart  = (ushort_t*)(ws + OFF_OP);
  float*    lpart  = (float*)(ws + OFF_LP);
  float*    e_buf  = (float*)(ws + OFF_EB);
  float*    sumExp = (float*)(ws + OFF_SE);

  qkv_mfma<<<dim3(NT, 5), 256, 0, stream>>>(x, Wq, bq, Wk, bk, Wv, bv, qT, kT, vG, sumExp);
  attn_kernel<<<dim3(NT, nsl), 512, 0, stream>>>(qT, kT, vG, Opart, lpart, base, rem);
  if (nsl == 7) cco_kernel<7><<<NT, 1024, 0, stream>>>(Opart, lpart, e_buf, sumExp);
  else          cco_kernel<4><<<NT, 1024, 0, stream>>>(Opart, lpart, e_buf, sumExp);
  final_mfma<<<dim3(NT, 4), 256, 0, stream>>>(x, W6, b6, gamma, e_buf, sumExp, out);
}

// Round 2
// 214.244 us; speedup vs baseline: 1.0775x; 1.0775x over previous
//
#include <hip/hip_runtime.h>

#define N 9216
#define CIN 256
#define DQ 32
#define NT 144                      // N / 64
#define LOG2E 1.44269504088896340736f

typedef short short8 __attribute__((ext_vector_type(8)));   // 8 bf16 in 4 VGPRs
typedef float floatx4 __attribute__((ext_vector_type(4)));
typedef unsigned short ushort_t;

__device__ __forceinline__ ushort_t f2bf(float f) {
  union { float f; unsigned u; } a; a.f = f;
  unsigned u = a.u;
  u += 0x7fffu + ((u >> 16) & 1u);   // round-to-nearest-even
  return (ushort_t)(u >> 16);
}
// cheap round-to-nearest: 2 VALU ops instead of 5.
__device__ __forceinline__ ushort_t f2bf_fast(float f) {
  union { float f; unsigned u; } a; a.f = f;
  return (ushort_t)((a.u + 0x8000u) >> 16);
}
__device__ __forceinline__ float bf2f(ushort_t h) {
  union { unsigned u; float f; } a; a.u = ((unsigned)h) << 16;
  return a.f;
}
// pack two floats -> one uint of 2 bf16 (lo = c, hi = c1)
__device__ __forceinline__ unsigned pack2(float lo, float hi) {
  return ((unsigned)f2bf_fast(hi) << 16) | (unsigned)f2bf_fast(lo);
}
// 8 consecutive fp32 -> bf16x8 A-fragment
__device__ __forceinline__ short8 mk_bf16x8(const float* p) {
  float4 f0 = *(const float4*)(p);
  float4 f1 = *(const float4*)(p + 4);
  union { unsigned u[4]; short8 v; } r;
  r.u[0] = pack2(f0.x, f0.y);
  r.u[1] = pack2(f0.z, f0.w);
  r.u[2] = pack2(f1.x, f1.y);
  r.u[3] = pack2(f1.z, f1.w);
  return r.v;
}

// ---------------------------------------------------------------------------
// Shared staging: x tile (256 c x 64 n) -> LDS bf16 xbT[n][k=c].
// ---------------------------------------------------------------------------
#define XBT_STRIDE 264   // ushorts per row (256 + 8 pad); 132 uints

__device__ __forceinline__ void stage_x_tile(
    const float* __restrict__ x, int n0, int t, ushort_t (*xbT)[XBT_STRIDE])
{
  const int p = t & 31, ng = t >> 5;          // ng in [0,8)
  unsigned* base = (unsigned*)&xbT[0][0] + (size_t)(ng * 8) * 132;
#pragma unroll
  for (int cc = 0; cc < 4; ++cc) {
    const int c = cc * 64 + 2 * p;
    const float* r0 = x + (size_t)c * N + n0 + ng * 8;
    const float* r1 = r0 + N;
    float4 a0 = *(const float4*)(r0);
    float4 a1 = *(const float4*)(r0 + 4);
    float4 b0 = *(const float4*)(r1);
    float4 b1 = *(const float4*)(r1 + 4);
    unsigned* d = base + (cc * 32 + p);
    d[0 * 132] = pack2(a0.x, b0.x);
    d[1 * 132] = pack2(a0.y, b0.y);
    d[2 * 132] = pack2(a0.z, b0.z);
    d[3 * 132] = pack2(a0.w, b0.w);
    d[4 * 132] = pack2(a1.x, b1.x);
    d[5 * 132] = pack2(a1.y, b1.y);
    d[6 * 132] = pack2(a1.z, b1.z);
    d[7 * 132] = pack2(a1.w, b1.w);
  }
}

// ---------------------------------------------------------------------------
// Kernel 1: q/k/v projections via bf16 MFMA.  UNCHANGED (control, R0 form).
// ---------------------------------------------------------------------------
__global__ __launch_bounds__(256) void qkv_mfma(
    const float* __restrict__ x,
    const float* __restrict__ Wq, const float* __restrict__ bq,
    const float* __restrict__ Wk, const float* __restrict__ bk,
    const float* __restrict__ Wv, const float* __restrict__ bv,
    ushort_t* __restrict__ qT, ushort_t* __restrict__ kT,
    ushort_t* __restrict__ vG, float* __restrict__ sumExp)
{
  if (blockIdx.x == 0 && blockIdx.y == 0 && threadIdx.x == 0) *sumExp = 0.f;

  __shared__ ushort_t xbT[64][XBT_STRIDE];
  const int t = threadIdx.x;
  const int n0 = blockIdx.x * 64;
  const int oc = blockIdx.y;                 // 0: q(32)+k(32); 1..4: v
  const int w = t >> 6, lane = t & 63;
  const int quad = lane >> 4, l15 = lane & 15;

  stage_x_tile(x, n0, t, xbT);
  __syncthreads();

  const int obase = oc * 64 + w * 16;
  const int oA = obase + l15;                // A-frag row (m = l15)
  const float* Arow;
  if (oc == 0) Arow = (obase < 32) ? (Wq + (size_t)oA * CIN)
                                   : (Wk + (size_t)(oA - 32) * CIN);
  else         Arow = Wv + (size_t)(oA - 64) * CIN;

  floatx4 acc[4];
#pragma unroll
  for (int b2 = 0; b2 < 4; ++b2) acc[b2] = (floatx4){0.f, 0.f, 0.f, 0.f};

#pragma unroll
  for (int ks = 0; ks < 8; ++ks) {
    const short8 af = mk_bf16x8(Arow + ks * 32 + 8 * quad);
#pragma unroll
    for (int b2 = 0; b2 < 4; ++b2) {
      const short8 bf = *(const short8*)&xbT[b2 * 16 + l15][ks * 32 + 8 * quad];
      acc[b2] = __builtin_amdgcn_mfma_f32_16x16x32_bf16(af, bf, acc[b2], 0, 0, 0);
    }
  }

  // Epilogue.  C-layout: col = l15 (n within subtile), row = 4*quad + r (o).
#pragma unroll
  for (int b2 = 0; b2 < 4; ++b2) {
    const int n = n0 + b2 * 16 + l15;
#pragma unroll
    for (int r = 0; r < 4; ++r) {
      const int o = obase + 4 * quad + r;
      const float val = acc[b2][r];
      if (oc == 0) {
        if (o < 32) qT[(size_t)n * DQ + o]        = f2bf((val + bq[o]) * LOG2E);
        else        kT[(size_t)n * DQ + (o - 32)] = f2bf(val + bk[o - 32]);
      } else        vG[(size_t)(o - 64) * N + n]  = f2bf(val + bv[o - 64]);
    }
  }
}

// ---------------------------------------------------------------------------
// Kernel 2: flash attention, 32-m tiles.  R2: 4 waves (R1's 8-wave split
// REGRESSED: occupancy 37->44 but dur 115->134 us -- not occupancy-bound).
// Software-pipelined one tile deep (T15): PV(t) runs one iteration behind
// QK(t+1), so the barrier no longer sits inside a same-iteration
// produce->consume chain.  kb/av prefetched a full body ahead into regs.
//   body(t): ds_read P(t) | prefetch kb(t+2),av(t+1) | QK(t+1) MFMA |
//            exp/pack -> ds_write P(t+1) (other buffer) | PV(t) | rotate | bar
// Pb double buffer makes this race-free (reads and writes always hit
// opposite buffers; one barrier per iter preserves WAR ordering).
// launch_bounds (256,3): ~170-reg cap, 12 waves/CU (same as R0).
// ---------------------------------------------------------------------------
__global__ __launch_bounds__(256, 3) void attn_kernel(
    const ushort_t* __restrict__ qT, const ushort_t* __restrict__ kT,
    const ushort_t* __restrict__ vG,
    ushort_t* __restrict__ Opart, float* __restrict__ lpart,
    int base, int rem)
{
  __shared__ ushort_t Pb[2][64][36];    // double-buffered P tile (64n x 32m)

  const int t = threadIdx.x;
  const int w = t >> 6;
  const int lane = t & 63;
  const int quad = lane >> 4;
  const int l15 = lane & 15;
  const int nt = blockIdx.x;
  const int s  = blockIdx.y;
  const int n0 = nt * 64;
  const int sliceIters = base + (s < rem ? 1 : 0);
  const int it0 = s * base + (s < rem ? s : rem);
  const int mbase = it0 * 32;
  const int cw = w * 64;

  const short8 aq =
      *(const short8*)(qT + (size_t)(n0 + 16 * w + l15) * DQ + 8 * quad);

  floatx4 acc[4][4];
#pragma unroll
  for (int a2 = 0; a2 < 4; ++a2)
#pragma unroll
    for (int b2 = 0; b2 < 4; ++b2)
      acc[a2][b2] = (floatx4){0.f, 0.f, 0.f, 0.f};
  float lsum[4] = {0.f, 0.f, 0.f, 0.f};
  const floatx4 z4 = {0.f, 0.f, 0.f, 0.f};

  // Streaming pointers.  kRow points at the NEXT K tile to load; vRow* at
  // the NEXT V tile to load.  Overshoot reads land in adjacent ws regions
  // (vG / Opart) -- allocated, data unused.
  const ushort_t* kRow  = kT + (size_t)(mbase + l15) * DQ + 8 * quad;
  const ushort_t* vRow0 = vG + (size_t)(cw +  0 + l15) * N + mbase + 8 * quad;
  const ushort_t* vRow1 = vG + (size_t)(cw + 16 + l15) * N + mbase + 8 * quad;
  const ushort_t* vRow2 = vG + (size_t)(cw + 32 + l15) * N + mbase + 8 * quad;
  const ushort_t* vRow3 = vG + (size_t)(cw + 48 + l15) * N + mbase + 8 * quad;

  // ---- prologue: QK(0) -> Pb[0]; load av(0) into avU; load kb(1) into kbU
  short8 k0 = *(const short8*)(kRow);
  short8 k1 = *(const short8*)(kRow + 16 * DQ);
  kRow += 32 * DQ;                                    // -> tile 1
  floatx4 s0 = __builtin_amdgcn_mfma_f32_16x16x32_bf16(aq, k0, z4, 0, 0, 0);
  floatx4 s1 = __builtin_amdgcn_mfma_f32_16x16x32_bf16(aq, k1, z4, 0, 0, 0);

  short8 avU0 = *(const short8*)(vRow0);
  short8 avU1 = *(const short8*)(vRow1);
  short8 avU2 = *(const short8*)(vRow2);
  short8 avU3 = *(const short8*)(vRow3);
  vRow0 += 32; vRow1 += 32; vRow2 += 32; vRow3 += 32; // -> tile 1

  short8 kbU0 = *(const short8*)(kRow);
  short8 kbU1 = *(const short8*)(kRow + 16 * DQ);
  kRow += 32 * DQ;                                    // -> tile 2

  {
    ushort_t* pb = &Pb[0][0][0];
#pragma unroll
    for (int r = 0; r < 4; ++r) {
      float p0 = exp2f(s0[r]);
      float p1 = exp2f(s1[r]);
      lsum[r] += p0 + p1;
      const int row = 16 * w + 4 * quad + r;
      pb[row * 36 + l15]      = f2bf_fast(p0);
      pb[row * 36 + 16 + l15] = f2bf_fast(p1);
    }
  }
  __syncthreads();

  // ---- main loop: body(t) for t = 0 .. sliceIters-2
  for (int it = 0; it < sliceIters - 1; ++it) {
    const ushort_t* pbR = &Pb[it & 1][0][0];
    ushort_t*       pbW = &Pb[(it + 1) & 1][0][0];

    // (1) P-frag reads for PV(t)
    union { uint2 u2[2]; short8 v; } pu0, pu1, pu2, pu3;
    {
      const ushort_t* pr0 = pbR + (0 * 16 + l15) * 36 + 8 * quad;
      const ushort_t* pr1 = pbR + (1 * 16 + l15) * 36 + 8 * quad;
      const ushort_t* pr2 = pbR + (2 * 16 + l15) * 36 + 8 * quad;
      const ushort_t* pr3 = pbR + (3 * 16 + l15) * 36 + 8 * quad;
      pu0.u2[0] = *(const uint2*)(pr0); pu0.u2[1] = *(const uint2*)(pr0 + 4);
      pu1.u2[0] = *(const uint2*)(pr1); pu1.u2[1] = *(const uint2*)(pr1 + 4);
      pu2.u2[0] = *(const uint2*)(pr2); pu2.u2[1] = *(const uint2*)(pr2 + 4);
      pu3.u2[0] = *(const uint2*)(pr3); pu3.u2[1] = *(const uint2*)(pr3 + 4);
    }

    // (2) prefetch kb(t+2), av(t+1)
    short8 kbV0 = *(const short8*)(kRow);
    short8 kbV1 = *(const short8*)(kRow + 16 * DQ);
    kRow += 32 * DQ;
    short8 avV0 = *(const short8*)(vRow0);
    short8 avV1 = *(const short8*)(vRow1);
    short8 avV2 = *(const short8*)(vRow2);
    short8 avV3 = *(const short8*)(vRow3);
    vRow0 += 32; vRow1 += 32; vRow2 += 32; vRow3 += 32;

    // (3) QK(t+1)
    floatx4 t0 = __builtin_amdgcn_mfma_f32_16x16x32_bf16(aq, kbU0, z4, 0, 0, 0);
    floatx4 t1 = __builtin_amdgcn_mfma_f32_16x16x32_bf16(aq, kbU1, z4, 0, 0, 0);

    // (4) exp/pack -> Pb[(t+1)&1], lsum
#pragma unroll
    for (int r = 0; r < 4; ++r) {
      float p0 = exp2f(t0[r]);
      float p1 = exp2f(t1[r]);
      lsum[r] += p0 + p1;
      const int row = 16 * w + 4 * quad + r;
      pbW[row * 36 + l15]      = f2bf_fast(p0);
      pbW[row * 36 + 16 + l15] = f2bf_fast(p1);
    }

    // (5) PV(t)
    __builtin_amdgcn_s_setprio(1);
    {
      const short8 pf0 = pu0.v, pf1 = pu1.v, pf2 = pu2.v, pf3 = pu3.v;
      acc[0][0] = __builtin_amdgcn_mfma_f32_16x16x32_bf16(avU0, pf0, acc[0][0], 0, 0, 0);
      acc[1][0] = __builtin_amdgcn_mfma_f32_16x16x32_bf16(avU1, pf0, acc[1][0], 0, 0, 0);
      acc[2][0] = __builtin_amdgcn_mfma_f32_16x16x32_bf16(avU2, pf0, acc[2][0], 0, 0, 0);
      acc[3][0] = __builtin_amdgcn_mfma_f32_16x16x32_bf16(avU3, pf0, acc[3][0], 0, 0, 0);
      acc[0][1] = __builtin_amdgcn_mfma_f32_16x16x32_bf16(avU0, pf1, acc[0][1], 0, 0, 0);
      acc[1][1] = __builtin_amdgcn_mfma_f32_16x16x32_bf16(avU1, pf1, acc[1][1], 0, 0, 0);
      acc[2][1] = __builtin_amdgcn_mfma_f32_16x16x32_bf16(avU2, pf1, acc[2][1], 0, 0, 0);
      acc[3][1] = __builtin_amdgcn_mfma_f32_16x16x32_bf16(avU3, pf1, acc[3][1], 0, 0, 0);
      acc[0][2] = __builtin_amdgcn_mfma_f32_16x16x32_bf16(avU0, pf2, acc[0][2], 0, 0, 0);
      acc[1][2] = __builtin_amdgcn_mfma_f32_16x16x32_bf16(avU1, pf2, acc[1][2], 0, 0, 0);
      acc[2][2] = __builtin_amdgcn_mfma_f32_16x16x32_bf16(avU2, pf2, acc[2][2], 0, 0, 0);
      acc[3][2] = __builtin_amdgcn_mfma_f32_16x16x32_bf16(avU3, pf2, acc[3][2], 0, 0, 0);
      acc[0][3] = __builtin_amdgcn_mfma_f32_16x16x32_bf16(avU0, pf3, acc[0][3], 0, 0, 0);
      acc[1][3] = __builtin_amdgcn_mfma_f32_16x16x32_bf16(avU1, pf3, acc[1][3], 0, 0, 0);
      acc[2][3] = __builtin_amdgcn_mfma_f32_16x16x32_bf16(avU2, pf3, acc[2][3], 0, 0, 0);
      acc[3][3] = __builtin_amdgcn_mfma_f32_16x16x32_bf16(avU3, pf3, acc[3][3], 0, 0, 0);
    }
    __builtin_amdgcn_s_setprio(0);

    // (6) rotate prefetch buffers
    kbU0 = kbV0; kbU1 = kbV1;
    avU0 = avV0; avU1 = avV1; avU2 = avV2; avU3 = avV3;

    __syncthreads();
  }

  // ---- epilogue: PV(sliceIters-1)
  {
    const ushort_t* pbR = &Pb[(sliceIters - 1) & 1][0][0];
    __builtin_amdgcn_s_setprio(1);
#pragma unroll
    for (int b2 = 0; b2 < 4; ++b2) {
      const ushort_t* pr = pbR + (b2 * 16 + l15) * 36 + 8 * quad;
      union { uint2 u2[2]; short8 v; } u;
      u.u2[0] = *(const uint2*)(pr);
      u.u2[1] = *(const uint2*)(pr + 4);
      const short8 pf = u.v;
      acc[0][b2] = __builtin_amdgcn_mfma_f32_16x16x32_bf16(avU0, pf, acc[0][b2], 0, 0, 0);
      acc[1][b2] = __builtin_amdgcn_mfma_f32_16x16x32_bf16(avU1, pf, acc[1][b2], 0, 0, 0);
      acc[2][b2] = __builtin_amdgcn_mfma_f32_16x16x32_bf16(avU2, pf, acc[2][b2], 0, 0, 0);
      acc[3][b2] = __builtin_amdgcn_mfma_f32_16x16x32_bf16(avU3, pf, acc[3][b2], 0, 0, 0);
    }
    __builtin_amdgcn_s_setprio(0);
  }

  // ---- lsum reduce (over l15 = m) and lpart write (R0 form)
#pragma unroll
  for (int r = 0; r < 4; ++r) {
    float v = lsum[r];
    v += __shfl_xor(v, 1);
    v += __shfl_xor(v, 2);
    v += __shfl_xor(v, 4);
    v += __shfl_xor(v, 8);
    lsum[r] = v;
  }
  if (l15 == 0) {
#pragma unroll
    for (int r = 0; r < 4; ++r)
      lpart[(size_t)s * N + n0 + 16 * w + 4 * quad + r] = lsum[r];
  }

  const size_t basep = ((size_t)s * NT + nt) * 256;
#pragma unroll
  for (int a2 = 0; a2 < 4; ++a2)
#pragma unroll
    for (int b2 = 0; b2 < 4; ++b2)
#pragma unroll
      for (int r = 0; r < 4; ++r) {
        const int c  = cw + a2 * 16 + 4 * quad + r;
        const int nl = b2 * 16 + l15;
        Opart[(basep + c) * 64 + nl] = f2bf(acc[a2][b2][r]);
      }
}

// ---------------------------------------------------------------------------
// Kernel 3: fused combine + gate-exp.  UNCHANGED (control).
// ---------------------------------------------------------------------------
template<int NSL>
__global__ __launch_bounds__(1024) void cco_kernel(
    const ushort_t* __restrict__ Opart, const float* __restrict__ lpart,
    float* __restrict__ e_buf, float* __restrict__ sumExp)
{
  const int nt = blockIdx.x;
  const int t = threadIdx.x;
  const int n = t & 63, ci = t >> 6;   // ci in [0,16)
  float mx = -3.4e38f, sm = 0.f;
#pragma unroll
  for (int k = 0; k < 16; ++k) {
    const int c = ci * 16 + k;
    float val = 0.f;
#pragma unroll
    for (int s2 = 0; s2 < NSL; ++s2)
      val += bf2f(Opart[(((size_t)s2 * NT + nt) * 256 + c) * 64 + n]);
    mx = fmaxf(mx, val);
    sm += val;
  }
  __shared__ float rmx[16][64], rsm[16][64];
  rmx[ci][n] = mx; rsm[ci][n] = sm;
  __syncthreads();
  if (t < 64) {
    float m = rmx[0][t], s = rsm[0][t];
#pragma unroll
    for (int g = 1; g < 16; ++g) { m = fmaxf(m, rmx[g][t]); s += rsm[g][t]; }
    float l = 0.f;
#pragma unroll
    for (int s3 = 0; s3 < NSL; ++s3) l += lpart[(size_t)s3 * N + nt * 64 + t];
    const float oc = (m + s * (1.0f / 256.0f)) / l;
    const float ev = exp2f(oc * (0.0625f * LOG2E));
    e_buf[nt * 64 + t] = ev;
    float vs = ev;
    vs += __shfl_xor(vs, 1);  vs += __shfl_xor(vs, 2);
    vs += __shfl_xor(vs, 4);  vs += __shfl_xor(vs, 8);
    vs += __shfl_xor(vs, 16); vs += __shfl_xor(vs, 32);
    if (t == 0) atomicAdd(sumExp, vs);
  }
}

// ---------------------------------------------------------------------------
// Kernel 4: final 1x1 conv via bf16 MFMA + fp32 epilogue.  UNCHANGED (control).
// ---------------------------------------------------------------------------
__global__ __launch_bounds__(256) void final_mfma(
    const float* __restrict__ x, const float* __restrict__ W6,
    const float* __restrict__ b6, const float* __restrict__ gamma,
    const float* __restrict__ e_buf, const float* __restrict__ sumExp,
    float* __restrict__ out)
{
  __shared__ ushort_t xbT[64][XBT_STRIDE];
  const int t = threadIdx.x;
  const int n0 = blockIdx.x * 64;
  const int w = t >> 6, lane = t & 63;
  const int quad = lane >> 4, l15 = lane & 15;

  stage_x_tile(x, n0, t, xbT);
  __syncthreads();

  const int obase = blockIdx.y * 64 + w * 16;
  const float* Arow = W6 + (size_t)(obase + l15) * CIN;

  floatx4 acc[4];
#pragma unroll
  for (int b2 = 0; b2 < 4; ++b2) acc[b2] = (floatx4){0.f, 0.f, 0.f, 0.f};

#pragma unroll
  for (int ks = 0; ks < 8; ++ks) {
    const short8 af = mk_bf16x8(Arow + ks * 32 + 8 * quad);
#pragma unroll
    for (int b2 = 0; b2 < 4; ++b2) {
      const short8 bf = *(const short8*)&xbT[b2 * 16 + l15][ks * 32 + 8 * quad];
      acc[b2] = __builtin_amdgcn_mfma_f32_16x16x32_bf16(af, bf, acc[b2], 0, 0, 0);
    }
  }

  const float g1 = 1.0f + gamma[0];
  const float inv = 1.0f / sumExp[0];
#pragma unroll
  for (int b2 = 0; b2 < 4; ++b2) {
    const int n = n0 + b2 * 16 + l15;
    const float xc = e_buf[n] * inv;
#pragma unroll
    for (int r = 0; r < 4; ++r) {
      const int o = obase + 4 * quad + r;
      const float xv = x[(size_t)o * N + n];
      out[(size_t)o * N + n] = xv + g1 * (xc * acc[b2][r] + b6[o]);
    }
  }
}

// ---------------------------------------------------------------------------
extern "C" void kernel_launch(void* const* d_in, const int* in_sizes, int n_in,
                              void* d_out, int out_size, void* d_ws, size_t ws_size,
                              hipStream_t stream)
{
  const float* x     = (const float*)d_in[0];
  const float* Wq    = (const float*)d_in[1];
  const float* bq    = (const float*)d_in[2];
  const float* Wk    = (const float*)d_in[3];
  const float* bk    = (const float*)d_in[4];
  const float* Wv    = (const float*)d_in[5];
  const float* bv    = (const float*)d_in[6];
  const float* W6    = (const float*)d_in[7];
  const float* b6    = (const float*)d_in[8];
  const float* gamma = (const float*)d_in[9];
  float* out = (float*)d_out;

  const size_t fixed = (size_t)N * DQ * 2 * 2        // qT,kT
                     + (size_t)CIN * N * 2            // vG
                     + (size_t)N * 4                  // e_buf
                     + 256;                           // sumExp (+pad)
  int nsl = 7;
  size_t need = fixed + (size_t)nsl * NT * 256 * 64 * 2 + (size_t)nsl * N * 4;
  if (ws_size < need) nsl = 4;
  const int totIters = N / 32;                        // 288
  const int base = totIters / nsl;
  const int rem  = totIters % nsl;

  char* ws = (char*)d_ws;
  const size_t OFF_QT = 0;
  const size_t OFF_KT = OFF_QT + (size_t)N * DQ * 2;
  const size_t OFF_V  = OFF_KT + (size_t)N * DQ * 2;
  const size_t OFF_OP = OFF_V  + (size_t)CIN * N * 2;
  const size_t OFF_LP = OFF_OP + (size_t)nsl * NT * 256 * 64 * 2;
  const size_t OFF_EB = OFF_LP + (size_t)nsl * N * 4;
  const size_t OFF_SE = OFF_EB + (size_t)N * 4;

  ushort_t* qT     = (ushort_t*)(ws + OFF_QT);
  ushort_t* kT     = (ushort_t*)(ws + OFF_KT);
  ushort_t* vG     = (ushort_t*)(ws + OFF_V);
  ushort_t* Opart  = (ushort_t*)(ws + OFF_OP);
  float*    lpart  = (float*)(ws + OFF_LP);
  float*    e_buf  = (float*)(ws + OFF_EB);
  float*    sumExp = (float*)(ws + OFF_SE);

  qkv_mfma<<<dim3(NT, 5), 256, 0, stream>>>(x, Wq, bq, Wk, bk, Wv, bv, qT, kT, vG, sumExp);
  attn_kernel<<<dim3(NT, nsl), 256, 0, stream>>>(qT, kT, vG, Opart, lpart, base, rem);
  if (nsl == 7) cco_kernel<7><<<NT, 1024, 0, stream>>>(Opart, lpart, e_buf, sumExp);
  else          cco_kernel<4><<<NT, 1024, 0, stream>>>(Opart, lpart, e_buf, sumExp);
  final_mfma<<<dim3(NT, 4), 256, 0, stream>>>(x, W6, b6, gamma, e_buf, sumExp, out);
}